// Round 3
// baseline (1759.282 us; speedup 1.0000x reference)
//
#include <hip/hip_runtime.h>

#define EPSV 1e-5f
#define BSH 6   // 64 nodes per bucket

// ---------------- bucketed CSR build ----------------
__global__ __launch_bounds__(256) void k_bhist(const int* __restrict__ dst, int E, int nb,
                                               int* __restrict__ bhist){
  extern __shared__ int lh[];
  for (int t = threadIdx.x; t < nb; t += 256) lh[t] = 0;
  __syncthreads();
  for (int e = blockIdx.x*256+threadIdx.x; e < E; e += gridDim.x*256)
    atomicAdd(&lh[dst[e]>>BSH], 1);
  __syncthreads();
  for (int t = threadIdx.x; t < nb; t += 256){ int v = lh[t]; if (v) atomicAdd(&bhist[t], v); }
}

// single-block exclusive scan of bhist[nb] -> boff, bcur ; boff[nb]=E ; rowptr[n]=E
__global__ __launch_bounds__(256) void k_bscan(const int* __restrict__ bhist, int nb,
                                               int* __restrict__ boff, int* __restrict__ bcur,
                                               int* __restrict__ rowptr, int n, int E){
  __shared__ int sh[2][256];
  int tid = threadIdx.x;
  int per = (nb + 255) / 256;          // <=8 for nb<=2048
  int base = tid*per;
  int v[8]; int s = 0;
  for (int j=0;j<per;++j){ int i=base+j; v[j] = (i<nb)? bhist[i]:0; s += v[j]; }
  sh[0][tid] = s; __syncthreads();
  int pa = 0;
  for (int off=1; off<256; off<<=1){
    int add = (tid>=off)? sh[pa][tid-off] : 0;
    sh[pa^1][tid] = sh[pa][tid] + add;
    pa ^= 1; __syncthreads();
  }
  int run = sh[pa][tid] - s;
  for (int j=0;j<per;++j){ int i=base+j; if (i<nb){ boff[i]=run; bcur[i]=run; run += v[j]; } }
  if (tid==255) boff[nb] = E;
  if (tid==254) rowptr[n] = E;
}

// scatter packed (ldst<<25 | src) into bucket regions
__global__ __launch_bounds__(256) void k_bscatter(const int* __restrict__ src, const int* __restrict__ dst,
                                                  int E, int nb, int nchunk,
                                                  int* __restrict__ bcur, unsigned* __restrict__ ebuf){
  extern __shared__ int lh[];
  int s = blockIdx.x*nchunk, e = min(E, s+nchunk);
  for (int t = threadIdx.x; t < nb; t += 256) lh[t] = 0;
  __syncthreads();
  for (int i = s+threadIdx.x; i < e; i += 256) atomicAdd(&lh[dst[i]>>BSH], 1);
  __syncthreads();
  for (int t = threadIdx.x; t < nb; t += 256){
    int v = lh[t];
    lh[t] = v ? atomicAdd(&bcur[t], v) : 0;
  }
  __syncthreads();
  for (int i = s+threadIdx.x; i < e; i += 256){
    int d = dst[i];
    int pos = atomicAdd(&lh[d>>BSH], 1);
    ebuf[pos] = (unsigned)src[i] | ((unsigned)(d & 63) << 25);
  }
}

// one block per bucket: counting sort -> col ; emits rowptr + dis
__global__ __launch_bounds__(256) void k_bsort(const unsigned* __restrict__ ebuf, const int* __restrict__ boff,
                                               int n, int* __restrict__ rowptr, int* __restrict__ col,
                                               float* __restrict__ dis){
  __shared__ int cnt[64]; __shared__ int cur[64];
  int b = blockIdx.x;
  int s = boff[b], e = boff[b+1];
  if (threadIdx.x < 64) cnt[threadIdx.x] = 0;
  __syncthreads();
  for (int i = s+threadIdx.x; i < e; i += 256) atomicAdd(&cnt[ebuf[i]>>25], 1);
  __syncthreads();
  if (threadIdx.x < 64){
    int v = cnt[threadIdx.x];
    int inc = v;
    for (int off=1; off<64; off<<=1){ int u = __shfl_up(inc, off); if (threadIdx.x >= off) inc += u; }
    int ex = inc - v;
    cur[threadIdx.x] = s + ex;
    int node = b*64 + threadIdx.x;
    if (node < n){ rowptr[node] = s + ex; dis[node] = rsqrtf((float)(v+1)); }
  }
  __syncthreads();
  for (int i = s+threadIdx.x; i < e; i += 256){
    unsigned w = ebuf[i];
    int pos = atomicAdd(&cur[w>>25], 1);
    col[pos] = (int)(w & 0x1FFFFFFu);
  }
}

// ---------------- graph segment offsets (batch is sorted) ----------------
__global__ __launch_bounds__(256) void k_gsinit(int* __restrict__ gs, int G, int n){
  for (int t = blockIdx.x*256+threadIdx.x; t<=G; t+=gridDim.x*256) gs[t] = n;
}
__global__ __launch_bounds__(256) void k_gsbound(const int* __restrict__ batch, int n, int* __restrict__ gs){
  for (int i = blockIdx.x*256+threadIdx.x; i<n; i+=gridDim.x*256){
    int b = batch[i];
    int prev = (i==0)? -1 : batch[i-1];
    for (int g = prev+1; g<=b; ++g) gs[g] = i;
  }
}

// ---------------- GEMM: out[i][:] = dis[i] * (bnrelu?(X[i,:]) @ W) ----------------
// wave handles 16 rows: 4 row-groups (rg) x 4 rows/lane; 16 col-quads (cg).
// Full compile-time K unroll -> loads are base+imm, deep pipeline.
template<int K, bool BN>
__global__ __launch_bounds__(256) void k_gemm(const float* __restrict__ X, const float* __restrict__ W,
    const float* __restrict__ dis, const float* __restrict__ stats,
    const float* __restrict__ g, const float* __restrict__ bt,
    float* __restrict__ out, int n, int ntiles)
{
  __shared__ float4 Wl[K*16];
  __shared__ float2 acS[64];
  for (int t = threadIdx.x; t < K*16; t += 256)
    Wl[t] = reinterpret_cast<const float4*>(W)[t];
  if (BN && threadIdx.x < 64){
    int j = threadIdx.x;
    float fn = (float)n;
    float mu = stats[j]/fn;
    float var = stats[64+j]/fn - mu*mu;
    float a = rsqrtf(var + EPSV) * g[j];
    acS[j] = make_float2(a, bt[j] - mu*a);
  }
  __syncthreads();
  int wave = threadIdx.x>>6, lane = threadIdx.x&63;
  int cg = lane&15, rg = lane>>4;
  for (int tile = blockIdx.x*4+wave; tile < ntiles; tile += gridDim.x*4){
    int r0 = tile*16 + rg*4;
    const float* X0 = X + (size_t)min(r0+0, n-1)*K;
    const float* X1 = X + (size_t)min(r0+1, n-1)*K;
    const float* X2 = X + (size_t)min(r0+2, n-1)*K;
    const float* X3 = X + (size_t)min(r0+3, n-1)*K;
    float4 a0 = make_float4(0.f,0.f,0.f,0.f);
    float4 a1 = a0, a2 = a0, a3 = a0;
    #pragma unroll
    for (int k=0; k<K; k+=4){
      float4 w0 = Wl[(k+0)*16+cg];
      float4 w1 = Wl[(k+1)*16+cg];
      float4 w2 = Wl[(k+2)*16+cg];
      float4 w3 = Wl[(k+3)*16+cg];
      float4 x0 = *reinterpret_cast<const float4*>(X0 + k);
      float4 x1 = *reinterpret_cast<const float4*>(X1 + k);
      float4 x2 = *reinterpret_cast<const float4*>(X2 + k);
      float4 x3 = *reinterpret_cast<const float4*>(X3 + k);
      if (BN){
        float2 p0 = acS[k], p1 = acS[k+1], p2 = acS[k+2], p3 = acS[k+3];
        x0.x = fmaxf(fmaf(x0.x,p0.x,p0.y),0.f); x0.y = fmaxf(fmaf(x0.y,p1.x,p1.y),0.f);
        x0.z = fmaxf(fmaf(x0.z,p2.x,p2.y),0.f); x0.w = fmaxf(fmaf(x0.w,p3.x,p3.y),0.f);
        x1.x = fmaxf(fmaf(x1.x,p0.x,p0.y),0.f); x1.y = fmaxf(fmaf(x1.y,p1.x,p1.y),0.f);
        x1.z = fmaxf(fmaf(x1.z,p2.x,p2.y),0.f); x1.w = fmaxf(fmaf(x1.w,p3.x,p3.y),0.f);
        x2.x = fmaxf(fmaf(x2.x,p0.x,p0.y),0.f); x2.y = fmaxf(fmaf(x2.y,p1.x,p1.y),0.f);
        x2.z = fmaxf(fmaf(x2.z,p2.x,p2.y),0.f); x2.w = fmaxf(fmaf(x2.w,p3.x,p3.y),0.f);
        x3.x = fmaxf(fmaf(x3.x,p0.x,p0.y),0.f); x3.y = fmaxf(fmaf(x3.y,p1.x,p1.y),0.f);
        x3.z = fmaxf(fmaf(x3.z,p2.x,p2.y),0.f); x3.w = fmaxf(fmaf(x3.w,p3.x,p3.y),0.f);
      }
      a0.x = fmaf(x0.w,w3.x, fmaf(x0.z,w2.x, fmaf(x0.y,w1.x, fmaf(x0.x,w0.x, a0.x))));
      a0.y = fmaf(x0.w,w3.y, fmaf(x0.z,w2.y, fmaf(x0.y,w1.y, fmaf(x0.x,w0.y, a0.y))));
      a0.z = fmaf(x0.w,w3.z, fmaf(x0.z,w2.z, fmaf(x0.y,w1.z, fmaf(x0.x,w0.z, a0.z))));
      a0.w = fmaf(x0.w,w3.w, fmaf(x0.z,w2.w, fmaf(x0.y,w1.w, fmaf(x0.x,w0.w, a0.w))));
      a1.x = fmaf(x1.w,w3.x, fmaf(x1.z,w2.x, fmaf(x1.y,w1.x, fmaf(x1.x,w0.x, a1.x))));
      a1.y = fmaf(x1.w,w3.y, fmaf(x1.z,w2.y, fmaf(x1.y,w1.y, fmaf(x1.x,w0.y, a1.y))));
      a1.z = fmaf(x1.w,w3.z, fmaf(x1.z,w2.z, fmaf(x1.y,w1.z, fmaf(x1.x,w0.z, a1.z))));
      a1.w = fmaf(x1.w,w3.w, fmaf(x1.z,w2.w, fmaf(x1.y,w1.w, fmaf(x1.x,w0.w, a1.w))));
      a2.x = fmaf(x2.w,w3.x, fmaf(x2.z,w2.x, fmaf(x2.y,w1.x, fmaf(x2.x,w0.x, a2.x))));
      a2.y = fmaf(x2.w,w3.y, fmaf(x2.z,w2.y, fmaf(x2.y,w1.y, fmaf(x2.x,w0.y, a2.y))));
      a2.z = fmaf(x2.w,w3.z, fmaf(x2.z,w2.z, fmaf(x2.y,w1.z, fmaf(x2.x,w0.z, a2.z))));
      a2.w = fmaf(x2.w,w3.w, fmaf(x2.z,w2.w, fmaf(x2.y,w1.w, fmaf(x2.x,w0.w, a2.w))));
      a3.x = fmaf(x3.w,w3.x, fmaf(x3.z,w2.x, fmaf(x3.y,w1.x, fmaf(x3.x,w0.x, a3.x))));
      a3.y = fmaf(x3.w,w3.y, fmaf(x3.z,w2.y, fmaf(x3.y,w1.y, fmaf(x3.x,w0.y, a3.y))));
      a3.z = fmaf(x3.w,w3.z, fmaf(x3.z,w2.z, fmaf(x3.y,w1.z, fmaf(x3.x,w0.z, a3.z))));
      a3.w = fmaf(x3.w,w3.w, fmaf(x3.z,w2.w, fmaf(x3.y,w1.w, fmaf(x3.x,w0.w, a3.w))));
    }
    if (r0+0 < n){ float d = dis[r0+0];
      *reinterpret_cast<float4*>(out + (size_t)(r0+0)*64 + cg*4) = make_float4(a0.x*d,a0.y*d,a0.z*d,a0.w*d); }
    if (r0+1 < n){ float d = dis[r0+1];
      *reinterpret_cast<float4*>(out + (size_t)(r0+1)*64 + cg*4) = make_float4(a1.x*d,a1.y*d,a1.z*d,a1.w*d); }
    if (r0+2 < n){ float d = dis[r0+2];
      *reinterpret_cast<float4*>(out + (size_t)(r0+2)*64 + cg*4) = make_float4(a2.x*d,a2.y*d,a2.z*d,a2.w*d); }
    if (r0+3 < n){ float d = dis[r0+3];
      *reinterpret_cast<float4*>(out + (size_t)(r0+3)*64 + cg*4) = make_float4(a3.x*d,a3.y*d,a3.z*d,a3.w*d); }
  }
}

// ---------------- aggregation + bias + BN-stat partials ----------------
__global__ __launch_bounds__(256) void k_agg(const float* __restrict__ H, const int* __restrict__ rp,
    const int* __restrict__ col, const float* __restrict__ dis, const float* __restrict__ bias,
    float* __restrict__ out, float* __restrict__ stats, int n)
{
  int wave = threadIdx.x>>6, lane = threadIdx.x&63;
  float bj = bias[lane];
  float bsum = 0.f, bsq = 0.f;
  int nw = gridDim.x*4;
  for (int i = blockIdx.x*4+wave; i<n; i+=nw){
    int s = rp[i], e = rp[i+1];
    float acc = H[(size_t)i*64+lane];
    int t = s;
    for (; t+8 <= e; t += 8){
      int c0 = col[t],   c1 = col[t+1], c2 = col[t+2], c3 = col[t+3];
      int c4 = col[t+4], c5 = col[t+5], c6 = col[t+6], c7 = col[t+7];
      float v0 = H[(size_t)c0*64+lane];
      float v1 = H[(size_t)c1*64+lane];
      float v2 = H[(size_t)c2*64+lane];
      float v3 = H[(size_t)c3*64+lane];
      float v4 = H[(size_t)c4*64+lane];
      float v5 = H[(size_t)c5*64+lane];
      float v6 = H[(size_t)c6*64+lane];
      float v7 = H[(size_t)c7*64+lane];
      acc += ((v0+v1)+(v2+v3)) + ((v4+v5)+(v6+v7));
    }
    for (; t+4 <= e; t += 4){
      int c0 = col[t], c1 = col[t+1], c2 = col[t+2], c3 = col[t+3];
      float v0 = H[(size_t)c0*64+lane];
      float v1 = H[(size_t)c1*64+lane];
      float v2 = H[(size_t)c2*64+lane];
      float v3 = H[(size_t)c3*64+lane];
      acc += (v0+v1)+(v2+v3);
    }
    for (; t<e; ++t) acc += H[(size_t)col[t]*64+lane];
    float v = fmaf(dis[i], acc, bj);
    out[(size_t)i*64+lane] = v;
    bsum += v; bsq = fmaf(v, v, bsq);
  }
  __shared__ float red[2][4][64];
  red[0][wave][lane] = bsum; red[1][wave][lane] = bsq;
  __syncthreads();
  if (wave==0){
    float s0 = (red[0][0][lane]+red[0][1][lane]) + (red[0][2][lane]+red[0][3][lane]);
    float q0 = (red[1][0][lane]+red[1][1][lane]) + (red[1][2][lane]+red[1][3][lane]);
    atomicAdd(&stats[lane], s0);
    atomicAdd(&stats[64+lane], q0);
  }
}

// ---------------- mean-pool with fused BN+ReLU ----------------
__global__ __launch_bounds__(256) void k_pool(const float* __restrict__ agg, const float* __restrict__ stats,
                                              const float* __restrict__ g, const float* __restrict__ bt,
                                              const int* __restrict__ gs, float* __restrict__ pooled, int n){
  __shared__ float2 acS[64];
  if (threadIdx.x < 64){
    int j = threadIdx.x;
    float fn = (float)n;
    float mu = stats[j]/fn;
    float var = stats[64+j]/fn - mu*mu;
    float a = rsqrtf(var + EPSV) * g[j];
    acS[j] = make_float2(a, bt[j] - mu*a);
  }
  __syncthreads();
  int gr = blockIdx.x;
  int s = gs[gr], e = gs[gr+1];
  int wave = threadIdx.x>>6, lane = threadIdx.x&63;
  float a = acS[lane].x, c = acS[lane].y;
  float acc = 0.f;
  for (int i = s+wave; i < e; i += 4)
    acc += fmaxf(fmaf(agg[(size_t)i*64+lane], a, c), 0.f);
  __shared__ float red[4][64];
  red[wave][lane] = acc; __syncthreads();
  if (wave==0){
    float t = (red[0][lane]+red[1][lane]) + (red[2][lane]+red[3][lane]);
    float cg = (float)(e - s);
    pooled[(size_t)gr*64+lane] = t / fmaxf(cg, 1.f);
  }
}

// ---------------- FC + log_softmax ----------------
__global__ __launch_bounds__(256) void k_logits(const float* __restrict__ pooled, const float* __restrict__ fcW,
                                                const float* __restrict__ fcb, float* __restrict__ out, int G){
  int gw = (blockIdx.x*256 + threadIdx.x) >> 6;
  int lane = threadIdx.x & 63;
  if (gw >= G) return;
  float l = -1e30f;
  if (lane < 10){
    l = fcb[lane];
    for (int k=0;k<64;++k) l = fmaf(pooled[(size_t)gw*64+k], fcW[k*10+lane], l);
  }
  float m = l;
  for (int off=32; off; off>>=1) m = fmaxf(m, __shfl_xor(m, off));
  float ex = (lane<10)? expf(l-m) : 0.f;
  float ssum = ex;
  for (int off=32; off; off>>=1) ssum += __shfl_xor(ssum, off);
  if (lane < 10) out[(size_t)gw*10+lane] = l - m - logf(ssum);
}

extern "C" void kernel_launch(void* const* d_in, const int* in_sizes, int n_in,
                              void* d_out, int out_size, void* d_ws, size_t ws_size,
                              hipStream_t stream){
  const float* x    = (const float*)d_in[0];
  const int*   ei   = (const int*)d_in[1];
  const int*   batch= (const int*)d_in[2];
  const float* W1 = (const float*)d_in[3];  const float* b1 = (const float*)d_in[4];
  const float* g1 = (const float*)d_in[5];  const float* bt1= (const float*)d_in[6];
  const float* W2 = (const float*)d_in[7];  const float* b2 = (const float*)d_in[8];
  const float* g2 = (const float*)d_in[9];  const float* bt2= (const float*)d_in[10];
  const float* W3 = (const float*)d_in[11]; const float* b3 = (const float*)d_in[12];
  const float* g3 = (const float*)d_in[13]; const float* bt3= (const float*)d_in[14];
  const float* W4 = (const float*)d_in[15]; const float* b4 = (const float*)d_in[16];
  const float* g4 = (const float*)d_in[17]; const float* bt4= (const float*)d_in[18];
  const float* fcW= (const float*)d_in[19]; const float* fcb= (const float*)d_in[20];

  int n = in_sizes[0] / 128;
  int E = in_sizes[1] / 2;
  int G = out_size / 10;
  const int* src = ei;
  const int* dst = ei + E;
  int nb = (n + 63) >> 6;

  // workspace carve (256B aligned)
  char* p = (char*)d_ws;
  auto alloc = [&](size_t bytes)->void*{ void* r = p; p += (bytes + 255) & ~(size_t)255; return r; };
  int*   bhist  = (int*)  alloc((size_t)nb*4);
  int*   boff   = (int*)  alloc((size_t)(nb+1)*4);
  int*   bcur   = (int*)  alloc((size_t)nb*4);
  int*   rowptr = (int*)  alloc((size_t)(n+1)*4);
  int*   col    = (int*)  alloc((size_t)E*4);
  float* dis    = (float*)alloc((size_t)n*4);
  float* bufB   = (float*)alloc((size_t)n*64*4);
  float* bufC   = (float*)alloc((size_t)n*64*4);
  float* stats  = (float*)alloc(4*128*4);
  int*   gs     = (int*)  alloc((size_t)(G+1)*4);
  float* pooled = (float*)alloc((size_t)G*64*4);
  unsigned* ebuf = (unsigned*)bufB;   // alias: dead before gemm1 writes bufB

  hipMemsetAsync(bhist, 0, (size_t)nb*4, stream);
  hipMemsetAsync(stats, 0, 4*128*4, stream);

  size_t ldsb = (size_t)nb*4;
  k_bhist<<<256,256,ldsb,stream>>>(dst, E, nb, bhist);
  k_bscan<<<1,256,0,stream>>>(bhist, nb, boff, bcur, rowptr, n, E);
  int nchunk = (E + 255) / 256;
  k_bscatter<<<256,256,ldsb,stream>>>(src, dst, E, nb, nchunk, bcur, ebuf);
  k_bsort<<<nb,256,0,stream>>>(ebuf, boff, n, rowptr, col, dis);
  k_gsinit<<<4,256,0,stream>>>(gs, G, n);
  k_gsbound<<<512,256,0,stream>>>(batch, n, gs);

  int ntiles = (n + 15) / 16;
  int gg  = (ntiles + 3) / 4;

  // layer 1
  k_gemm<128,false><<<gg,256,0,stream>>>(x, W1, dis, nullptr, nullptr, nullptr, bufB, n, ntiles);
  k_agg<<<2048,256,0,stream>>>(bufB, rowptr, col, dis, b1, bufC, stats+0, n);
  // layer 2
  k_gemm<64,true><<<gg,256,0,stream>>>(bufC, W2, dis, stats+0, g2, bt2, bufB, n, ntiles);
  k_agg<<<2048,256,0,stream>>>(bufB, rowptr, col, dis, b2, bufC, stats+128, n);
  // layer 3
  k_gemm<64,true><<<gg,256,0,stream>>>(bufC, W3, dis, stats+128, g3, bt3, bufB, n, ntiles);
  k_agg<<<2048,256,0,stream>>>(bufB, rowptr, col, dis, b3, bufC, stats+256, n);
  // layer 4
  k_gemm<64,true><<<gg,256,0,stream>>>(bufC, W4, dis, stats+256, g4, bt4, bufB, n, ntiles);
  k_agg<<<2048,256,0,stream>>>(bufB, rowptr, col, dis, b4, bufC, stats+384, n);

  k_pool<<<G,256,0,stream>>>(bufC, stats+384, g4, bt4, gs, pooled, n);
  k_logits<<<(G*64 + 255)/256,256,0,stream>>>(pooled, fcW, fcb, (float*)d_out, G);
}

// Round 4
// 631.655 us; speedup vs baseline: 2.7852x; 2.7852x over previous
//
#include <hip/hip_runtime.h>

#define EPSV 1e-5f
#define BSH 6   // 64 nodes per bucket

// ---------------- bucketed CSR build ----------------
__global__ __launch_bounds__(256) void k_bhist(const int* __restrict__ dst, int E, int nb,
                                               int* __restrict__ bhist){
  extern __shared__ int lh[];
  for (int t = threadIdx.x; t < nb; t += 256) lh[t] = 0;
  __syncthreads();
  for (int e = blockIdx.x*256+threadIdx.x; e < E; e += gridDim.x*256)
    atomicAdd(&lh[dst[e]>>BSH], 1);
  __syncthreads();
  for (int t = threadIdx.x; t < nb; t += 256){ int v = lh[t]; if (v) atomicAdd(&bhist[t], v); }
}

// single-block exclusive scan of bhist[nb] -> boff, bcur ; boff[nb]=E ; rowptr[n]=E
__global__ __launch_bounds__(256) void k_bscan(const int* __restrict__ bhist, int nb,
                                               int* __restrict__ boff, int* __restrict__ bcur,
                                               int* __restrict__ rowptr, int n, int E){
  __shared__ int sh[2][256];
  int tid = threadIdx.x;
  int per = (nb + 255) / 256;          // <=8 for nb<=2048
  int base = tid*per;
  int v[8]; int s = 0;
  for (int j=0;j<per;++j){ int i=base+j; v[j] = (i<nb)? bhist[i]:0; s += v[j]; }
  sh[0][tid] = s; __syncthreads();
  int pa = 0;
  for (int off=1; off<256; off<<=1){
    int add = (tid>=off)? sh[pa][tid-off] : 0;
    sh[pa^1][tid] = sh[pa][tid] + add;
    pa ^= 1; __syncthreads();
  }
  int run = sh[pa][tid] - s;
  for (int j=0;j<per;++j){ int i=base+j; if (i<nb){ boff[i]=run; bcur[i]=run; run += v[j]; } }
  if (tid==255) boff[nb] = E;
  if (tid==254) rowptr[n] = E;
}

// scatter packed (ldst<<25 | src) into bucket regions
__global__ __launch_bounds__(256) void k_bscatter(const int* __restrict__ src, const int* __restrict__ dst,
                                                  int E, int nb, int nchunk,
                                                  int* __restrict__ bcur, unsigned* __restrict__ ebuf){
  extern __shared__ int lh[];
  int s = blockIdx.x*nchunk, e = min(E, s+nchunk);
  for (int t = threadIdx.x; t < nb; t += 256) lh[t] = 0;
  __syncthreads();
  for (int i = s+threadIdx.x; i < e; i += 256) atomicAdd(&lh[dst[i]>>BSH], 1);
  __syncthreads();
  for (int t = threadIdx.x; t < nb; t += 256){
    int v = lh[t];
    lh[t] = v ? atomicAdd(&bcur[t], v) : 0;
  }
  __syncthreads();
  for (int i = s+threadIdx.x; i < e; i += 256){
    int d = dst[i];
    int pos = atomicAdd(&lh[d>>BSH], 1);
    ebuf[pos] = (unsigned)src[i] | ((unsigned)(d & 63) << 25);
  }
}

// one block per bucket: counting sort -> col ; emits rowptr + dis
__global__ __launch_bounds__(256) void k_bsort(const unsigned* __restrict__ ebuf, const int* __restrict__ boff,
                                               int n, int* __restrict__ rowptr, int* __restrict__ col,
                                               float* __restrict__ dis){
  __shared__ int cnt[64]; __shared__ int cur[64];
  int b = blockIdx.x;
  int s = boff[b], e = boff[b+1];
  if (threadIdx.x < 64) cnt[threadIdx.x] = 0;
  __syncthreads();
  for (int i = s+threadIdx.x; i < e; i += 256) atomicAdd(&cnt[ebuf[i]>>25], 1);
  __syncthreads();
  if (threadIdx.x < 64){
    int v = cnt[threadIdx.x];
    int inc = v;
    for (int off=1; off<64; off<<=1){ int u = __shfl_up(inc, off); if (threadIdx.x >= off) inc += u; }
    int ex = inc - v;
    cur[threadIdx.x] = s + ex;
    int node = b*64 + threadIdx.x;
    if (node < n){ rowptr[node] = s + ex; dis[node] = rsqrtf((float)(v+1)); }
  }
  __syncthreads();
  for (int i = s+threadIdx.x; i < e; i += 256){
    unsigned w = ebuf[i];
    int pos = atomicAdd(&cur[w>>25], 1);
    col[pos] = (int)(w & 0x1FFFFFFu);
  }
}

// ---------------- graph segment offsets (batch is sorted) ----------------
__global__ __launch_bounds__(256) void k_gsinit(int* __restrict__ gs, int G, int n){
  for (int t = blockIdx.x*256+threadIdx.x; t<=G; t+=gridDim.x*256) gs[t] = n;
}
__global__ __launch_bounds__(256) void k_gsbound(const int* __restrict__ batch, int n, int* __restrict__ gs){
  for (int i = blockIdx.x*256+threadIdx.x; i<n; i+=gridDim.x*256){
    int b = batch[i];
    int prev = (i==0)? -1 : batch[i-1];
    for (int g = prev+1; g<=b; ++g) gs[g] = i;
  }
}

// ---------------- GEMM: out[i][:] = dis[i] * (bnrelu?(X[i,:]) @ W) ----------------
// wave = 16 rows: 4 row-groups x 4 rows; 16 col-quads. 2-deep explicit prefetch,
// bounded unroll (spill-safe: ~100 VGPR).
template<int K, bool BN>
__global__ __launch_bounds__(256) void k_gemm(const float* __restrict__ X, const float* __restrict__ W,
    const float* __restrict__ dis, const float* __restrict__ stats,
    const float* __restrict__ g, const float* __restrict__ bt,
    float* __restrict__ out, int n, int ntiles)
{
  __shared__ float4 Wl[K*16];
  __shared__ float2 acS[64];
  for (int t = threadIdx.x; t < K*16; t += 256)
    Wl[t] = reinterpret_cast<const float4*>(W)[t];
  if (BN && threadIdx.x < 64){
    int j = threadIdx.x;
    float fn = (float)n;
    float mu = stats[j]/fn;
    float var = stats[64+j]/fn - mu*mu;
    float a = rsqrtf(var + EPSV) * g[j];
    acS[j] = make_float2(a, bt[j] - mu*a);
  }
  __syncthreads();
  int wave = threadIdx.x>>6, lane = threadIdx.x&63;
  int cg = lane&15, rg = lane>>4;

  for (int tile = blockIdx.x*4+wave; tile < ntiles; tile += gridDim.x*4){
    int r0 = tile*16 + rg*4;
    const float* X0 = X + (size_t)min(r0+0, n-1)*K;
    const float* X1 = X + (size_t)min(r0+1, n-1)*K;
    const float* X2 = X + (size_t)min(r0+2, n-1)*K;
    const float* X3 = X + (size_t)min(r0+3, n-1)*K;
    float4 a0 = make_float4(0.f,0.f,0.f,0.f);
    float4 a1 = a0, a2 = a0, a3 = a0;
    // current x-quads
    float4 c0 = *reinterpret_cast<const float4*>(X0);
    float4 c1 = *reinterpret_cast<const float4*>(X1);
    float4 c2 = *reinterpret_cast<const float4*>(X2);
    float4 c3 = *reinterpret_cast<const float4*>(X3);
    #pragma unroll 2
    for (int k=0; k<K-4; k+=4){
      // prefetch next quad (independent of this iteration's FMAs)
      float4 n0 = *reinterpret_cast<const float4*>(X0 + k + 4);
      float4 n1 = *reinterpret_cast<const float4*>(X1 + k + 4);
      float4 n2 = *reinterpret_cast<const float4*>(X2 + k + 4);
      float4 n3 = *reinterpret_cast<const float4*>(X3 + k + 4);
      float4 w0 = Wl[(k+0)*16+cg];
      float4 w1 = Wl[(k+1)*16+cg];
      float4 w2 = Wl[(k+2)*16+cg];
      float4 w3 = Wl[(k+3)*16+cg];
      if (BN){
        float2 p0 = acS[k], p1 = acS[k+1], p2 = acS[k+2], p3 = acS[k+3];
        c0.x = fmaxf(fmaf(c0.x,p0.x,p0.y),0.f); c0.y = fmaxf(fmaf(c0.y,p1.x,p1.y),0.f);
        c0.z = fmaxf(fmaf(c0.z,p2.x,p2.y),0.f); c0.w = fmaxf(fmaf(c0.w,p3.x,p3.y),0.f);
        c1.x = fmaxf(fmaf(c1.x,p0.x,p0.y),0.f); c1.y = fmaxf(fmaf(c1.y,p1.x,p1.y),0.f);
        c1.z = fmaxf(fmaf(c1.z,p2.x,p2.y),0.f); c1.w = fmaxf(fmaf(c1.w,p3.x,p3.y),0.f);
        c2.x = fmaxf(fmaf(c2.x,p0.x,p0.y),0.f); c2.y = fmaxf(fmaf(c2.y,p1.x,p1.y),0.f);
        c2.z = fmaxf(fmaf(c2.z,p2.x,p2.y),0.f); c2.w = fmaxf(fmaf(c2.w,p3.x,p3.y),0.f);
        c3.x = fmaxf(fmaf(c3.x,p0.x,p0.y),0.f); c3.y = fmaxf(fmaf(c3.y,p1.x,p1.y),0.f);
        c3.z = fmaxf(fmaf(c3.z,p2.x,p2.y),0.f); c3.w = fmaxf(fmaf(c3.w,p3.x,p3.y),0.f);
      }
      a0.x = fmaf(c0.w,w3.x, fmaf(c0.z,w2.x, fmaf(c0.y,w1.x, fmaf(c0.x,w0.x, a0.x))));
      a0.y = fmaf(c0.w,w3.y, fmaf(c0.z,w2.y, fmaf(c0.y,w1.y, fmaf(c0.x,w0.y, a0.y))));
      a0.z = fmaf(c0.w,w3.z, fmaf(c0.z,w2.z, fmaf(c0.y,w1.z, fmaf(c0.x,w0.z, a0.z))));
      a0.w = fmaf(c0.w,w3.w, fmaf(c0.z,w2.w, fmaf(c0.y,w1.w, fmaf(c0.x,w0.w, a0.w))));
      a1.x = fmaf(c1.w,w3.x, fmaf(c1.z,w2.x, fmaf(c1.y,w1.x, fmaf(c1.x,w0.x, a1.x))));
      a1.y = fmaf(c1.w,w3.y, fmaf(c1.z,w2.y, fmaf(c1.y,w1.y, fmaf(c1.x,w0.y, a1.y))));
      a1.z = fmaf(c1.w,w3.z, fmaf(c1.z,w2.z, fmaf(c1.y,w1.z, fmaf(c1.x,w0.z, a1.z))));
      a1.w = fmaf(c1.w,w3.w, fmaf(c1.z,w2.w, fmaf(c1.y,w1.w, fmaf(c1.x,w0.w, a1.w))));
      a2.x = fmaf(c2.w,w3.x, fmaf(c2.z,w2.x, fmaf(c2.y,w1.x, fmaf(c2.x,w0.x, a2.x))));
      a2.y = fmaf(c2.w,w3.y, fmaf(c2.z,w2.y, fmaf(c2.y,w1.y, fmaf(c2.x,w0.y, a2.y))));
      a2.z = fmaf(c2.w,w3.z, fmaf(c2.z,w2.z, fmaf(c2.y,w1.z, fmaf(c2.x,w0.z, a2.z))));
      a2.w = fmaf(c2.w,w3.w, fmaf(c2.z,w2.w, fmaf(c2.y,w1.w, fmaf(c2.x,w0.w, a2.w))));
      a3.x = fmaf(c3.w,w3.x, fmaf(c3.z,w2.x, fmaf(c3.y,w1.x, fmaf(c3.x,w0.x, a3.x))));
      a3.y = fmaf(c3.w,w3.y, fmaf(c3.z,w2.y, fmaf(c3.y,w1.y, fmaf(c3.x,w0.y, a3.y))));
      a3.z = fmaf(c3.w,w3.z, fmaf(c3.z,w2.z, fmaf(c3.y,w1.z, fmaf(c3.x,w0.z, a3.z))));
      a3.w = fmaf(c3.w,w3.w, fmaf(c3.z,w2.w, fmaf(c3.y,w1.w, fmaf(c3.x,w0.w, a3.w))));
      c0 = n0; c1 = n1; c2 = n2; c3 = n3;
    }
    { // epilogue: last k-quad (k = K-4), no prefetch
      const int k = K-4;
      float4 w0 = Wl[(k+0)*16+cg];
      float4 w1 = Wl[(k+1)*16+cg];
      float4 w2 = Wl[(k+2)*16+cg];
      float4 w3 = Wl[(k+3)*16+cg];
      if (BN){
        float2 p0 = acS[k], p1 = acS[k+1], p2 = acS[k+2], p3 = acS[k+3];
        c0.x = fmaxf(fmaf(c0.x,p0.x,p0.y),0.f); c0.y = fmaxf(fmaf(c0.y,p1.x,p1.y),0.f);
        c0.z = fmaxf(fmaf(c0.z,p2.x,p2.y),0.f); c0.w = fmaxf(fmaf(c0.w,p3.x,p3.y),0.f);
        c1.x = fmaxf(fmaf(c1.x,p0.x,p0.y),0.f); c1.y = fmaxf(fmaf(c1.y,p1.x,p1.y),0.f);
        c1.z = fmaxf(fmaf(c1.z,p2.x,p2.y),0.f); c1.w = fmaxf(fmaf(c1.w,p3.x,p3.y),0.f);
        c2.x = fmaxf(fmaf(c2.x,p0.x,p0.y),0.f); c2.y = fmaxf(fmaf(c2.y,p1.x,p1.y),0.f);
        c2.z = fmaxf(fmaf(c2.z,p2.x,p2.y),0.f); c2.w = fmaxf(fmaf(c2.w,p3.x,p3.y),0.f);
        c3.x = fmaxf(fmaf(c3.x,p0.x,p0.y),0.f); c3.y = fmaxf(fmaf(c3.y,p1.x,p1.y),0.f);
        c3.z = fmaxf(fmaf(c3.z,p2.x,p2.y),0.f); c3.w = fmaxf(fmaf(c3.w,p3.x,p3.y),0.f);
      }
      a0.x = fmaf(c0.w,w3.x, fmaf(c0.z,w2.x, fmaf(c0.y,w1.x, fmaf(c0.x,w0.x, a0.x))));
      a0.y = fmaf(c0.w,w3.y, fmaf(c0.z,w2.y, fmaf(c0.y,w1.y, fmaf(c0.x,w0.y, a0.y))));
      a0.z = fmaf(c0.w,w3.z, fmaf(c0.z,w2.z, fmaf(c0.y,w1.z, fmaf(c0.x,w0.z, a0.z))));
      a0.w = fmaf(c0.w,w3.w, fmaf(c0.z,w2.w, fmaf(c0.y,w1.w, fmaf(c0.x,w0.w, a0.w))));
      a1.x = fmaf(c1.w,w3.x, fmaf(c1.z,w2.x, fmaf(c1.y,w1.x, fmaf(c1.x,w0.x, a1.x))));
      a1.y = fmaf(c1.w,w3.y, fmaf(c1.z,w2.y, fmaf(c1.y,w1.y, fmaf(c1.x,w0.y, a1.y))));
      a1.z = fmaf(c1.w,w3.z, fmaf(c1.z,w2.z, fmaf(c1.y,w1.z, fmaf(c1.x,w0.z, a1.z))));
      a1.w = fmaf(c1.w,w3.w, fmaf(c1.z,w2.w, fmaf(c1.y,w1.w, fmaf(c1.x,w0.w, a1.w))));
      a2.x = fmaf(c2.w,w3.x, fmaf(c2.z,w2.x, fmaf(c2.y,w1.x, fmaf(c2.x,w0.x, a2.x))));
      a2.y = fmaf(c2.w,w3.y, fmaf(c2.z,w2.y, fmaf(c2.y,w1.y, fmaf(c2.x,w0.y, a2.y))));
      a2.z = fmaf(c2.w,w3.z, fmaf(c2.z,w2.z, fmaf(c2.y,w1.z, fmaf(c2.x,w0.z, a2.z))));
      a2.w = fmaf(c2.w,w3.w, fmaf(c2.z,w2.w, fmaf(c2.y,w1.w, fmaf(c2.x,w0.w, a2.w))));
      a3.x = fmaf(c3.w,w3.x, fmaf(c3.z,w2.x, fmaf(c3.y,w1.x, fmaf(c3.x,w0.x, a3.x))));
      a3.y = fmaf(c3.w,w3.y, fmaf(c3.z,w2.y, fmaf(c3.y,w1.y, fmaf(c3.x,w0.y, a3.y))));
      a3.z = fmaf(c3.w,w3.z, fmaf(c3.z,w2.z, fmaf(c3.y,w1.z, fmaf(c3.x,w0.z, a3.z))));
      a3.w = fmaf(c3.w,w3.w, fmaf(c3.z,w2.w, fmaf(c3.y,w1.w, fmaf(c3.x,w0.w, a3.w))));
    }
    if (r0+0 < n){ float d = dis[r0+0];
      *reinterpret_cast<float4*>(out + (size_t)(r0+0)*64 + cg*4) = make_float4(a0.x*d,a0.y*d,a0.z*d,a0.w*d); }
    if (r0+1 < n){ float d = dis[r0+1];
      *reinterpret_cast<float4*>(out + (size_t)(r0+1)*64 + cg*4) = make_float4(a1.x*d,a1.y*d,a1.z*d,a1.w*d); }
    if (r0+2 < n){ float d = dis[r0+2];
      *reinterpret_cast<float4*>(out + (size_t)(r0+2)*64 + cg*4) = make_float4(a2.x*d,a2.y*d,a2.z*d,a2.w*d); }
    if (r0+3 < n){ float d = dis[r0+3];
      *reinterpret_cast<float4*>(out + (size_t)(r0+3)*64 + cg*4) = make_float4(a3.x*d,a3.y*d,a3.z*d,a3.w*d); }
  }
}

// ---------------- aggregation + bias + BN-stat partials ----------------
__global__ __launch_bounds__(256) void k_agg(const float* __restrict__ H, const int* __restrict__ rp,
    const int* __restrict__ col, const float* __restrict__ dis, const float* __restrict__ bias,
    float* __restrict__ out, float* __restrict__ stats, int n)
{
  int wave = threadIdx.x>>6, lane = threadIdx.x&63;
  float bj = bias[lane];
  float bsum = 0.f, bsq = 0.f;
  int nw = gridDim.x*4;
  for (int i = blockIdx.x*4+wave; i<n; i+=nw){
    int s = rp[i], e = rp[i+1];
    float acc = H[(size_t)i*64+lane];
    int t = s;
    for (; t+8 <= e; t += 8){
      int c0 = col[t],   c1 = col[t+1], c2 = col[t+2], c3 = col[t+3];
      int c4 = col[t+4], c5 = col[t+5], c6 = col[t+6], c7 = col[t+7];
      float v0 = H[(size_t)c0*64+lane];
      float v1 = H[(size_t)c1*64+lane];
      float v2 = H[(size_t)c2*64+lane];
      float v3 = H[(size_t)c3*64+lane];
      float v4 = H[(size_t)c4*64+lane];
      float v5 = H[(size_t)c5*64+lane];
      float v6 = H[(size_t)c6*64+lane];
      float v7 = H[(size_t)c7*64+lane];
      acc += ((v0+v1)+(v2+v3)) + ((v4+v5)+(v6+v7));
    }
    for (; t+4 <= e; t += 4){
      int c0 = col[t], c1 = col[t+1], c2 = col[t+2], c3 = col[t+3];
      float v0 = H[(size_t)c0*64+lane];
      float v1 = H[(size_t)c1*64+lane];
      float v2 = H[(size_t)c2*64+lane];
      float v3 = H[(size_t)c3*64+lane];
      acc += (v0+v1)+(v2+v3);
    }
    for (; t<e; ++t) acc += H[(size_t)col[t]*64+lane];
    float v = fmaf(dis[i], acc, bj);
    out[(size_t)i*64+lane] = v;
    bsum += v; bsq = fmaf(v, v, bsq);
  }
  __shared__ float red[2][4][64];
  red[0][wave][lane] = bsum; red[1][wave][lane] = bsq;
  __syncthreads();
  if (wave==0){
    float s0 = (red[0][0][lane]+red[0][1][lane]) + (red[0][2][lane]+red[0][3][lane]);
    float q0 = (red[1][0][lane]+red[1][1][lane]) + (red[1][2][lane]+red[1][3][lane]);
    atomicAdd(&stats[lane], s0);
    atomicAdd(&stats[64+lane], q0);
  }
}

// ---------------- mean-pool with fused BN+ReLU ----------------
__global__ __launch_bounds__(256) void k_pool(const float* __restrict__ agg, const float* __restrict__ stats,
                                              const float* __restrict__ g, const float* __restrict__ bt,
                                              const int* __restrict__ gs, float* __restrict__ pooled, int n){
  __shared__ float2 acS[64];
  if (threadIdx.x < 64){
    int j = threadIdx.x;
    float fn = (float)n;
    float mu = stats[j]/fn;
    float var = stats[64+j]/fn - mu*mu;
    float a = rsqrtf(var + EPSV) * g[j];
    acS[j] = make_float2(a, bt[j] - mu*a);
  }
  __syncthreads();
  int gr = blockIdx.x;
  int s = gs[gr], e = gs[gr+1];
  int wave = threadIdx.x>>6, lane = threadIdx.x&63;
  float a = acS[lane].x, c = acS[lane].y;
  float acc = 0.f;
  for (int i = s+wave; i < e; i += 4)
    acc += fmaxf(fmaf(agg[(size_t)i*64+lane], a, c), 0.f);
  __shared__ float red[4][64];
  red[wave][lane] = acc; __syncthreads();
  if (wave==0){
    float t = (red[0][lane]+red[1][lane]) + (red[2][lane]+red[3][lane]);
    float cg = (float)(e - s);
    pooled[(size_t)gr*64+lane] = t / fmaxf(cg, 1.f);
  }
}

// ---------------- FC + log_softmax ----------------
__global__ __launch_bounds__(256) void k_logits(const float* __restrict__ pooled, const float* __restrict__ fcW,
                                                const float* __restrict__ fcb, float* __restrict__ out, int G){
  int gw = (blockIdx.x*256 + threadIdx.x) >> 6;
  int lane = threadIdx.x & 63;
  if (gw >= G) return;
  float l = -1e30f;
  if (lane < 10){
    l = fcb[lane];
    for (int k=0;k<64;++k) l = fmaf(pooled[(size_t)gw*64+k], fcW[k*10+lane], l);
  }
  float m = l;
  for (int off=32; off; off>>=1) m = fmaxf(m, __shfl_xor(m, off));
  float ex = (lane<10)? expf(l-m) : 0.f;
  float ssum = ex;
  for (int off=32; off; off>>=1) ssum += __shfl_xor(ssum, off);
  if (lane < 10) out[(size_t)gw*10+lane] = l - m - logf(ssum);
}

extern "C" void kernel_launch(void* const* d_in, const int* in_sizes, int n_in,
                              void* d_out, int out_size, void* d_ws, size_t ws_size,
                              hipStream_t stream){
  const float* x    = (const float*)d_in[0];
  const int*   ei   = (const int*)d_in[1];
  const int*   batch= (const int*)d_in[2];
  const float* W1 = (const float*)d_in[3];  const float* b1 = (const float*)d_in[4];
  const float* g1 = (const float*)d_in[5];  const float* bt1= (const float*)d_in[6];
  const float* W2 = (const float*)d_in[7];  const float* b2 = (const float*)d_in[8];
  const float* g2 = (const float*)d_in[9];  const float* bt2= (const float*)d_in[10];
  const float* W3 = (const float*)d_in[11]; const float* b3 = (const float*)d_in[12];
  const float* g3 = (const float*)d_in[13]; const float* bt3= (const float*)d_in[14];
  const float* W4 = (const float*)d_in[15]; const float* b4 = (const float*)d_in[16];
  const float* g4 = (const float*)d_in[17]; const float* bt4= (const float*)d_in[18];
  const float* fcW= (const float*)d_in[19]; const float* fcb= (const float*)d_in[20];

  int n = in_sizes[0] / 128;
  int E = in_sizes[1] / 2;
  int G = out_size / 10;
  const int* src = ei;
  const int* dst = ei + E;
  int nb = (n + 63) >> 6;

  // workspace carve (256B aligned)
  char* p = (char*)d_ws;
  auto alloc = [&](size_t bytes)->void*{ void* r = p; p += (bytes + 255) & ~(size_t)255; return r; };
  int*   bhist  = (int*)  alloc((size_t)nb*4);
  int*   boff   = (int*)  alloc((size_t)(nb+1)*4);
  int*   bcur   = (int*)  alloc((size_t)nb*4);
  int*   rowptr = (int*)  alloc((size_t)(n+1)*4);
  int*   col    = (int*)  alloc((size_t)E*4);
  float* dis    = (float*)alloc((size_t)n*4);
  float* bufB   = (float*)alloc((size_t)n*64*4);
  float* bufC   = (float*)alloc((size_t)n*64*4);
  float* stats  = (float*)alloc(4*128*4);
  int*   gs     = (int*)  alloc((size_t)(G+1)*4);
  float* pooled = (float*)alloc((size_t)G*64*4);
  unsigned* ebuf = (unsigned*)bufB;   // alias: dead before gemm1 writes bufB

  hipMemsetAsync(bhist, 0, (size_t)nb*4, stream);
  hipMemsetAsync(stats, 0, 4*128*4, stream);

  size_t ldsb = (size_t)nb*4;
  k_bhist<<<256,256,ldsb,stream>>>(dst, E, nb, bhist);
  k_bscan<<<1,256,0,stream>>>(bhist, nb, boff, bcur, rowptr, n, E);
  int nchunk = (E + 255) / 256;
  k_bscatter<<<256,256,ldsb,stream>>>(src, dst, E, nb, nchunk, bcur, ebuf);
  k_bsort<<<nb,256,0,stream>>>(ebuf, boff, n, rowptr, col, dis);
  k_gsinit<<<4,256,0,stream>>>(gs, G, n);
  k_gsbound<<<512,256,0,stream>>>(batch, n, gs);

  int ntiles = (n + 15) / 16;
  int gg  = (ntiles + 3) / 4;

  // layer 1
  k_gemm<128,false><<<gg,256,0,stream>>>(x, W1, dis, nullptr, nullptr, nullptr, bufB, n, ntiles);
  k_agg<<<2048,256,0,stream>>>(bufB, rowptr, col, dis, b1, bufC, stats+0, n);
  // layer 2
  k_gemm<64,true><<<gg,256,0,stream>>>(bufC, W2, dis, stats+0, g2, bt2, bufB, n, ntiles);
  k_agg<<<2048,256,0,stream>>>(bufB, rowptr, col, dis, b2, bufC, stats+128, n);
  // layer 3
  k_gemm<64,true><<<gg,256,0,stream>>>(bufC, W3, dis, stats+128, g3, bt3, bufB, n, ntiles);
  k_agg<<<2048,256,0,stream>>>(bufB, rowptr, col, dis, b3, bufC, stats+256, n);
  // layer 4
  k_gemm<64,true><<<gg,256,0,stream>>>(bufC, W4, dis, stats+256, g4, bt4, bufB, n, ntiles);
  k_agg<<<2048,256,0,stream>>>(bufB, rowptr, col, dis, b4, bufC, stats+384, n);

  k_pool<<<G,256,0,stream>>>(bufC, stats+384, g4, bt4, gs, pooled, n);
  k_logits<<<(G*64 + 255)/256,256,0,stream>>>(pooled, fcW, fcb, (float*)d_out, G);
}

// Round 5
// 568.070 us; speedup vs baseline: 3.0969x; 1.1119x over previous
//
#include <hip/hip_runtime.h>
#include <hip/hip_bf16.h>

#define EPSV 1e-5f
#define BSH 6   // 64 nodes per bucket

struct alignas(8) bf4 { __hip_bfloat16 x,y,z,w; };

// ---------------- bucketed CSR build ----------------
__global__ __launch_bounds__(256) void k_bhist(const int* __restrict__ dst, int E, int nb,
                                               int* __restrict__ bhist){
  extern __shared__ int lh[];
  for (int t = threadIdx.x; t < nb; t += 256) lh[t] = 0;
  __syncthreads();
  for (int e = blockIdx.x*256+threadIdx.x; e < E; e += gridDim.x*256)
    atomicAdd(&lh[dst[e]>>BSH], 1);
  __syncthreads();
  for (int t = threadIdx.x; t < nb; t += 256){ int v = lh[t]; if (v) atomicAdd(&bhist[t], v); }
}

// single-block exclusive scan of bhist[nb] -> boff, bcur ; boff[nb]=E ; rowptr[n]=E
__global__ __launch_bounds__(256) void k_bscan(const int* __restrict__ bhist, int nb,
                                               int* __restrict__ boff, int* __restrict__ bcur,
                                               int* __restrict__ rowptr, int n, int E){
  __shared__ int sh[2][256];
  int tid = threadIdx.x;
  int per = (nb + 255) / 256;          // <=8 for nb<=2048
  int base = tid*per;
  int v[8]; int s = 0;
  for (int j=0;j<per;++j){ int i=base+j; v[j] = (i<nb)? bhist[i]:0; s += v[j]; }
  sh[0][tid] = s; __syncthreads();
  int pa = 0;
  for (int off=1; off<256; off<<=1){
    int add = (tid>=off)? sh[pa][tid-off] : 0;
    sh[pa^1][tid] = sh[pa][tid] + add;
    pa ^= 1; __syncthreads();
  }
  int run = sh[pa][tid] - s;
  for (int j=0;j<per;++j){ int i=base+j; if (i<nb){ boff[i]=run; bcur[i]=run; run += v[j]; } }
  if (tid==255) boff[nb] = E;
  if (tid==254) rowptr[n] = E;
}

// scatter packed (ldst<<25 | src) into bucket regions
__global__ __launch_bounds__(256) void k_bscatter(const int* __restrict__ src, const int* __restrict__ dst,
                                                  int E, int nb, int nchunk,
                                                  int* __restrict__ bcur, unsigned* __restrict__ ebuf){
  extern __shared__ int lh[];
  int s = blockIdx.x*nchunk, e = min(E, s+nchunk);
  for (int t = threadIdx.x; t < nb; t += 256) lh[t] = 0;
  __syncthreads();
  for (int i = s+threadIdx.x; i < e; i += 256) atomicAdd(&lh[dst[i]>>BSH], 1);
  __syncthreads();
  for (int t = threadIdx.x; t < nb; t += 256){
    int v = lh[t];
    lh[t] = v ? atomicAdd(&bcur[t], v) : 0;
  }
  __syncthreads();
  for (int i = s+threadIdx.x; i < e; i += 256){
    int d = dst[i];
    int pos = atomicAdd(&lh[d>>BSH], 1);
    ebuf[pos] = (unsigned)src[i] | ((unsigned)(d & 63) << 25);
  }
}

// one block per bucket: counting sort -> col ; emits rowptr + dis
__global__ __launch_bounds__(256) void k_bsort(const unsigned* __restrict__ ebuf, const int* __restrict__ boff,
                                               int n, int* __restrict__ rowptr, int* __restrict__ col,
                                               float* __restrict__ dis){
  __shared__ int cnt[64]; __shared__ int cur[64];
  int b = blockIdx.x;
  int s = boff[b], e = boff[b+1];
  if (threadIdx.x < 64) cnt[threadIdx.x] = 0;
  __syncthreads();
  for (int i = s+threadIdx.x; i < e; i += 256) atomicAdd(&cnt[ebuf[i]>>25], 1);
  __syncthreads();
  if (threadIdx.x < 64){
    int v = cnt[threadIdx.x];
    int inc = v;
    for (int off=1; off<64; off<<=1){ int u = __shfl_up(inc, off); if (threadIdx.x >= off) inc += u; }
    int ex = inc - v;
    cur[threadIdx.x] = s + ex;
    int node = b*64 + threadIdx.x;
    if (node < n){ rowptr[node] = s + ex; dis[node] = rsqrtf((float)(v+1)); }
  }
  __syncthreads();
  for (int i = s+threadIdx.x; i < e; i += 256){
    unsigned w = ebuf[i];
    int pos = atomicAdd(&cur[w>>25], 1);
    col[pos] = (int)(w & 0x1FFFFFFu);
  }
}

// ---------------- graph segment offsets (batch is sorted) ----------------
__global__ __launch_bounds__(256) void k_gsinit(int* __restrict__ gs, int G, int n){
  for (int t = blockIdx.x*256+threadIdx.x; t<=G; t+=gridDim.x*256) gs[t] = n;
}
__global__ __launch_bounds__(256) void k_gsbound(const int* __restrict__ batch, int n, int* __restrict__ gs){
  for (int i = blockIdx.x*256+threadIdx.x; i<n; i+=gridDim.x*256){
    int b = batch[i];
    int prev = (i==0)? -1 : batch[i-1];
    for (int g = prev+1; g<=b; ++g) gs[g] = i;
  }
}

// ---------------- GEMM: out[i][:] = bf16( dis[i] * (bnrelu?(X[i,:]) @ W) ) ----------------
// wave = 16 rows: 4 row-groups x 4 rows; 16 col-quads. 2-deep explicit prefetch.
template<int K, bool BN>
__global__ __launch_bounds__(256) void k_gemm(const float* __restrict__ X, const float* __restrict__ W,
    const float* __restrict__ dis, const float* __restrict__ stats,
    const float* __restrict__ g, const float* __restrict__ bt,
    __hip_bfloat16* __restrict__ out, int n, int ntiles)
{
  __shared__ float4 Wl[K*16];
  __shared__ float2 acS[64];
  for (int t = threadIdx.x; t < K*16; t += 256)
    Wl[t] = reinterpret_cast<const float4*>(W)[t];
  if (BN && threadIdx.x < 64){
    int j = threadIdx.x;
    float fn = (float)n;
    float mu = stats[j]/fn;
    float var = stats[64+j]/fn - mu*mu;
    float a = rsqrtf(var + EPSV) * g[j];
    acS[j] = make_float2(a, bt[j] - mu*a);
  }
  __syncthreads();
  int wave = threadIdx.x>>6, lane = threadIdx.x&63;
  int cg = lane&15, rg = lane>>4;

  for (int tile = blockIdx.x*4+wave; tile < ntiles; tile += gridDim.x*4){
    int r0 = tile*16 + rg*4;
    const float* X0 = X + (size_t)min(r0+0, n-1)*K;
    const float* X1 = X + (size_t)min(r0+1, n-1)*K;
    const float* X2 = X + (size_t)min(r0+2, n-1)*K;
    const float* X3 = X + (size_t)min(r0+3, n-1)*K;
    float4 a0 = make_float4(0.f,0.f,0.f,0.f);
    float4 a1 = a0, a2 = a0, a3 = a0;
    float4 c0 = *reinterpret_cast<const float4*>(X0);
    float4 c1 = *reinterpret_cast<const float4*>(X1);
    float4 c2 = *reinterpret_cast<const float4*>(X2);
    float4 c3 = *reinterpret_cast<const float4*>(X3);
    #pragma unroll 2
    for (int k=0; k<K-4; k+=4){
      float4 n0 = *reinterpret_cast<const float4*>(X0 + k + 4);
      float4 n1 = *reinterpret_cast<const float4*>(X1 + k + 4);
      float4 n2 = *reinterpret_cast<const float4*>(X2 + k + 4);
      float4 n3 = *reinterpret_cast<const float4*>(X3 + k + 4);
      float4 w0 = Wl[(k+0)*16+cg];
      float4 w1 = Wl[(k+1)*16+cg];
      float4 w2 = Wl[(k+2)*16+cg];
      float4 w3 = Wl[(k+3)*16+cg];
      if (BN){
        float2 p0 = acS[k], p1 = acS[k+1], p2 = acS[k+2], p3 = acS[k+3];
        c0.x = fmaxf(fmaf(c0.x,p0.x,p0.y),0.f); c0.y = fmaxf(fmaf(c0.y,p1.x,p1.y),0.f);
        c0.z = fmaxf(fmaf(c0.z,p2.x,p2.y),0.f); c0.w = fmaxf(fmaf(c0.w,p3.x,p3.y),0.f);
        c1.x = fmaxf(fmaf(c1.x,p0.x,p0.y),0.f); c1.y = fmaxf(fmaf(c1.y,p1.x,p1.y),0.f);
        c1.z = fmaxf(fmaf(c1.z,p2.x,p2.y),0.f); c1.w = fmaxf(fmaf(c1.w,p3.x,p3.y),0.f);
        c2.x = fmaxf(fmaf(c2.x,p0.x,p0.y),0.f); c2.y = fmaxf(fmaf(c2.y,p1.x,p1.y),0.f);
        c2.z = fmaxf(fmaf(c2.z,p2.x,p2.y),0.f); c2.w = fmaxf(fmaf(c2.w,p3.x,p3.y),0.f);
        c3.x = fmaxf(fmaf(c3.x,p0.x,p0.y),0.f); c3.y = fmaxf(fmaf(c3.y,p1.x,p1.y),0.f);
        c3.z = fmaxf(fmaf(c3.z,p2.x,p2.y),0.f); c3.w = fmaxf(fmaf(c3.w,p3.x,p3.y),0.f);
      }
      a0.x = fmaf(c0.w,w3.x, fmaf(c0.z,w2.x, fmaf(c0.y,w1.x, fmaf(c0.x,w0.x, a0.x))));
      a0.y = fmaf(c0.w,w3.y, fmaf(c0.z,w2.y, fmaf(c0.y,w1.y, fmaf(c0.x,w0.y, a0.y))));
      a0.z = fmaf(c0.w,w3.z, fmaf(c0.z,w2.z, fmaf(c0.y,w1.z, fmaf(c0.x,w0.z, a0.z))));
      a0.w = fmaf(c0.w,w3.w, fmaf(c0.z,w2.w, fmaf(c0.y,w1.w, fmaf(c0.x,w0.w, a0.w))));
      a1.x = fmaf(c1.w,w3.x, fmaf(c1.z,w2.x, fmaf(c1.y,w1.x, fmaf(c1.x,w0.x, a1.x))));
      a1.y = fmaf(c1.w,w3.y, fmaf(c1.z,w2.y, fmaf(c1.y,w1.y, fmaf(c1.x,w0.y, a1.y))));
      a1.z = fmaf(c1.w,w3.z, fmaf(c1.z,w2.z, fmaf(c1.y,w1.z, fmaf(c1.x,w0.z, a1.z))));
      a1.w = fmaf(c1.w,w3.w, fmaf(c1.z,w2.w, fmaf(c1.y,w1.w, fmaf(c1.x,w0.w, a1.w))));
      a2.x = fmaf(c2.w,w3.x, fmaf(c2.z,w2.x, fmaf(c2.y,w1.x, fmaf(c2.x,w0.x, a2.x))));
      a2.y = fmaf(c2.w,w3.y, fmaf(c2.z,w2.y, fmaf(c2.y,w1.y, fmaf(c2.x,w0.y, a2.y))));
      a2.z = fmaf(c2.w,w3.z, fmaf(c2.z,w2.z, fmaf(c2.y,w1.z, fmaf(c2.x,w0.z, a2.z))));
      a2.w = fmaf(c2.w,w3.w, fmaf(c2.z,w2.w, fmaf(c2.y,w1.w, fmaf(c2.x,w0.w, a2.w))));
      a3.x = fmaf(c3.w,w3.x, fmaf(c3.z,w2.x, fmaf(c3.y,w1.x, fmaf(c3.x,w0.x, a3.x))));
      a3.y = fmaf(c3.w,w3.y, fmaf(c3.z,w2.y, fmaf(c3.y,w1.y, fmaf(c3.x,w0.y, a3.y))));
      a3.z = fmaf(c3.w,w3.z, fmaf(c3.z,w2.z, fmaf(c3.y,w1.z, fmaf(c3.x,w0.z, a3.z))));
      a3.w = fmaf(c3.w,w3.w, fmaf(c3.z,w2.w, fmaf(c3.y,w1.w, fmaf(c3.x,w0.w, a3.w))));
      c0 = n0; c1 = n1; c2 = n2; c3 = n3;
    }
    { // epilogue: last k-quad
      const int k = K-4;
      float4 w0 = Wl[(k+0)*16+cg];
      float4 w1 = Wl[(k+1)*16+cg];
      float4 w2 = Wl[(k+2)*16+cg];
      float4 w3 = Wl[(k+3)*16+cg];
      if (BN){
        float2 p0 = acS[k], p1 = acS[k+1], p2 = acS[k+2], p3 = acS[k+3];
        c0.x = fmaxf(fmaf(c0.x,p0.x,p0.y),0.f); c0.y = fmaxf(fmaf(c0.y,p1.x,p1.y),0.f);
        c0.z = fmaxf(fmaf(c0.z,p2.x,p2.y),0.f); c0.w = fmaxf(fmaf(c0.w,p3.x,p3.y),0.f);
        c1.x = fmaxf(fmaf(c1.x,p0.x,p0.y),0.f); c1.y = fmaxf(fmaf(c1.y,p1.x,p1.y),0.f);
        c1.z = fmaxf(fmaf(c1.z,p2.x,p2.y),0.f); c1.w = fmaxf(fmaf(c1.w,p3.x,p3.y),0.f);
        c2.x = fmaxf(fmaf(c2.x,p0.x,p0.y),0.f); c2.y = fmaxf(fmaf(c2.y,p1.x,p1.y),0.f);
        c2.z = fmaxf(fmaf(c2.z,p2.x,p2.y),0.f); c2.w = fmaxf(fmaf(c2.w,p3.x,p3.y),0.f);
        c3.x = fmaxf(fmaf(c3.x,p0.x,p0.y),0.f); c3.y = fmaxf(fmaf(c3.y,p1.x,p1.y),0.f);
        c3.z = fmaxf(fmaf(c3.z,p2.x,p2.y),0.f); c3.w = fmaxf(fmaf(c3.w,p3.x,p3.y),0.f);
      }
      a0.x = fmaf(c0.w,w3.x, fmaf(c0.z,w2.x, fmaf(c0.y,w1.x, fmaf(c0.x,w0.x, a0.x))));
      a0.y = fmaf(c0.w,w3.y, fmaf(c0.z,w2.y, fmaf(c0.y,w1.y, fmaf(c0.x,w0.y, a0.y))));
      a0.z = fmaf(c0.w,w3.z, fmaf(c0.z,w2.z, fmaf(c0.y,w1.z, fmaf(c0.x,w0.z, a0.z))));
      a0.w = fmaf(c0.w,w3.w, fmaf(c0.z,w2.w, fmaf(c0.y,w1.w, fmaf(c0.x,w0.w, a0.w))));
      a1.x = fmaf(c1.w,w3.x, fmaf(c1.z,w2.x, fmaf(c1.y,w1.x, fmaf(c1.x,w0.x, a1.x))));
      a1.y = fmaf(c1.w,w3.y, fmaf(c1.z,w2.y, fmaf(c1.y,w1.y, fmaf(c1.x,w0.y, a1.y))));
      a1.z = fmaf(c1.w,w3.z, fmaf(c1.z,w2.z, fmaf(c1.y,w1.z, fmaf(c1.x,w0.z, a1.z))));
      a1.w = fmaf(c1.w,w3.w, fmaf(c1.z,w2.w, fmaf(c1.y,w1.w, fmaf(c1.x,w0.w, a1.w))));
      a2.x = fmaf(c2.w,w3.x, fmaf(c2.z,w2.x, fmaf(c2.y,w1.x, fmaf(c2.x,w0.x, a2.x))));
      a2.y = fmaf(c2.w,w3.y, fmaf(c2.z,w2.y, fmaf(c2.y,w1.y, fmaf(c2.x,w0.y, a2.y))));
      a2.z = fmaf(c2.w,w3.z, fmaf(c2.z,w2.z, fmaf(c2.y,w1.z, fmaf(c2.x,w0.z, a2.z))));
      a2.w = fmaf(c2.w,w3.w, fmaf(c2.z,w2.w, fmaf(c2.y,w1.w, fmaf(c2.x,w0.w, a2.w))));
      a3.x = fmaf(c3.w,w3.x, fmaf(c3.z,w2.x, fmaf(c3.y,w1.x, fmaf(c3.x,w0.x, a3.x))));
      a3.y = fmaf(c3.w,w3.y, fmaf(c3.z,w2.y, fmaf(c3.y,w1.y, fmaf(c3.x,w0.y, a3.y))));
      a3.z = fmaf(c3.w,w3.z, fmaf(c3.z,w2.z, fmaf(c3.y,w1.z, fmaf(c3.x,w0.z, a3.z))));
      a3.w = fmaf(c3.w,w3.w, fmaf(c3.z,w2.w, fmaf(c3.y,w1.w, fmaf(c3.x,w0.w, a3.w))));
    }
    if (r0+0 < n){ float d = dis[r0+0];
      bf4 o{__float2bfloat16(a0.x*d),__float2bfloat16(a0.y*d),__float2bfloat16(a0.z*d),__float2bfloat16(a0.w*d)};
      *reinterpret_cast<bf4*>(out + (size_t)(r0+0)*64 + cg*4) = o; }
    if (r0+1 < n){ float d = dis[r0+1];
      bf4 o{__float2bfloat16(a1.x*d),__float2bfloat16(a1.y*d),__float2bfloat16(a1.z*d),__float2bfloat16(a1.w*d)};
      *reinterpret_cast<bf4*>(out + (size_t)(r0+1)*64 + cg*4) = o; }
    if (r0+2 < n){ float d = dis[r0+2];
      bf4 o{__float2bfloat16(a2.x*d),__float2bfloat16(a2.y*d),__float2bfloat16(a2.z*d),__float2bfloat16(a2.w*d)};
      *reinterpret_cast<bf4*>(out + (size_t)(r0+2)*64 + cg*4) = o; }
    if (r0+3 < n){ float d = dis[r0+3];
      bf4 o{__float2bfloat16(a3.x*d),__float2bfloat16(a3.y*d),__float2bfloat16(a3.z*d),__float2bfloat16(a3.w*d)};
      *reinterpret_cast<bf4*>(out + (size_t)(r0+3)*64 + cg*4) = o; }
  }
}

// ---------------- aggregation + bias + BN-stat partials (bf16 gather, fp32 accum) ----------------
__global__ __launch_bounds__(256) void k_agg(const __hip_bfloat16* __restrict__ H, const int* __restrict__ rp,
    const int* __restrict__ col, const float* __restrict__ dis, const float* __restrict__ bias,
    float* __restrict__ out, float* __restrict__ stats, int n)
{
  int wave = threadIdx.x>>6, lane = threadIdx.x&63;
  float bj = bias[lane];
  float bsum = 0.f, bsq = 0.f;
  int nw = gridDim.x*4;
  for (int i = blockIdx.x*4+wave; i<n; i+=nw){
    int s = rp[i], e = rp[i+1];
    float acc = __bfloat162float(H[(size_t)i*64+lane]);
    int t = s;
    for (; t+8 <= e; t += 8){
      int c0 = col[t],   c1 = col[t+1], c2 = col[t+2], c3 = col[t+3];
      int c4 = col[t+4], c5 = col[t+5], c6 = col[t+6], c7 = col[t+7];
      float v0 = __bfloat162float(H[(size_t)c0*64+lane]);
      float v1 = __bfloat162float(H[(size_t)c1*64+lane]);
      float v2 = __bfloat162float(H[(size_t)c2*64+lane]);
      float v3 = __bfloat162float(H[(size_t)c3*64+lane]);
      float v4 = __bfloat162float(H[(size_t)c4*64+lane]);
      float v5 = __bfloat162float(H[(size_t)c5*64+lane]);
      float v6 = __bfloat162float(H[(size_t)c6*64+lane]);
      float v7 = __bfloat162float(H[(size_t)c7*64+lane]);
      acc += ((v0+v1)+(v2+v3)) + ((v4+v5)+(v6+v7));
    }
    for (; t+4 <= e; t += 4){
      int c0 = col[t], c1 = col[t+1], c2 = col[t+2], c3 = col[t+3];
      float v0 = __bfloat162float(H[(size_t)c0*64+lane]);
      float v1 = __bfloat162float(H[(size_t)c1*64+lane]);
      float v2 = __bfloat162float(H[(size_t)c2*64+lane]);
      float v3 = __bfloat162float(H[(size_t)c3*64+lane]);
      acc += (v0+v1)+(v2+v3);
    }
    for (; t<e; ++t) acc += __bfloat162float(H[(size_t)col[t]*64+lane]);
    float v = fmaf(dis[i], acc, bj);
    out[(size_t)i*64+lane] = v;
    bsum += v; bsq = fmaf(v, v, bsq);
  }
  __shared__ float red[2][4][64];
  red[0][wave][lane] = bsum; red[1][wave][lane] = bsq;
  __syncthreads();
  if (wave==0){
    float s0 = (red[0][0][lane]+red[0][1][lane]) + (red[0][2][lane]+red[0][3][lane]);
    float q0 = (red[1][0][lane]+red[1][1][lane]) + (red[1][2][lane]+red[1][3][lane]);
    atomicAdd(&stats[lane], s0);
    atomicAdd(&stats[64+lane], q0);
  }
}

// ---------------- mean-pool with fused BN+ReLU ----------------
__global__ __launch_bounds__(256) void k_pool(const float* __restrict__ agg, const float* __restrict__ stats,
                                              const float* __restrict__ g, const float* __restrict__ bt,
                                              const int* __restrict__ gs, float* __restrict__ pooled, int n){
  __shared__ float2 acS[64];
  if (threadIdx.x < 64){
    int j = threadIdx.x;
    float fn = (float)n;
    float mu = stats[j]/fn;
    float var = stats[64+j]/fn - mu*mu;
    float a = rsqrtf(var + EPSV) * g[j];
    acS[j] = make_float2(a, bt[j] - mu*a);
  }
  __syncthreads();
  int gr = blockIdx.x;
  int s = gs[gr], e = gs[gr+1];
  int wave = threadIdx.x>>6, lane = threadIdx.x&63;
  float a = acS[lane].x, c = acS[lane].y;
  float acc = 0.f;
  for (int i = s+wave; i < e; i += 4)
    acc += fmaxf(fmaf(agg[(size_t)i*64+lane], a, c), 0.f);
  __shared__ float red[4][64];
  red[wave][lane] = acc; __syncthreads();
  if (wave==0){
    float t = (red[0][lane]+red[1][lane]) + (red[2][lane]+red[3][lane]);
    float cg = (float)(e - s);
    pooled[(size_t)gr*64+lane] = t / fmaxf(cg, 1.f);
  }
}

// ---------------- FC + log_softmax ----------------
__global__ __launch_bounds__(256) void k_logits(const float* __restrict__ pooled, const float* __restrict__ fcW,
                                                const float* __restrict__ fcb, float* __restrict__ out, int G){
  int gw = (blockIdx.x*256 + threadIdx.x) >> 6;
  int lane = threadIdx.x & 63;
  if (gw >= G) return;
  float l = -1e30f;
  if (lane < 10){
    l = fcb[lane];
    for (int k=0;k<64;++k) l = fmaf(pooled[(size_t)gw*64+k], fcW[k*10+lane], l);
  }
  float m = l;
  for (int off=32; off; off>>=1) m = fmaxf(m, __shfl_xor(m, off));
  float ex = (lane<10)? expf(l-m) : 0.f;
  float ssum = ex;
  for (int off=32; off; off>>=1) ssum += __shfl_xor(ssum, off);
  if (lane < 10) out[(size_t)gw*10+lane] = l - m - logf(ssum);
}

extern "C" void kernel_launch(void* const* d_in, const int* in_sizes, int n_in,
                              void* d_out, int out_size, void* d_ws, size_t ws_size,
                              hipStream_t stream){
  const float* x    = (const float*)d_in[0];
  const int*   ei   = (const int*)d_in[1];
  const int*   batch= (const int*)d_in[2];
  const float* W1 = (const float*)d_in[3];  const float* b1 = (const float*)d_in[4];
  const float* g1 = (const float*)d_in[5];  const float* bt1= (const float*)d_in[6];
  const float* W2 = (const float*)d_in[7];  const float* b2 = (const float*)d_in[8];
  const float* g2 = (const float*)d_in[9];  const float* bt2= (const float*)d_in[10];
  const float* W3 = (const float*)d_in[11]; const float* b3 = (const float*)d_in[12];
  const float* g3 = (const float*)d_in[13]; const float* bt3= (const float*)d_in[14];
  const float* W4 = (const float*)d_in[15]; const float* b4 = (const float*)d_in[16];
  const float* g4 = (const float*)d_in[17]; const float* bt4= (const float*)d_in[18];
  const float* fcW= (const float*)d_in[19]; const float* fcb= (const float*)d_in[20];

  int n = in_sizes[0] / 128;
  int E = in_sizes[1] / 2;
  int G = out_size / 10;
  const int* src = ei;
  const int* dst = ei + E;
  int nb = (n + 63) >> 6;

  // workspace carve (256B aligned)
  char* p = (char*)d_ws;
  auto alloc = [&](size_t bytes)->void*{ void* r = p; p += (bytes + 255) & ~(size_t)255; return r; };
  int*   bhist  = (int*)  alloc((size_t)nb*4);
  int*   boff   = (int*)  alloc((size_t)(nb+1)*4);
  int*   bcur   = (int*)  alloc((size_t)nb*4);
  int*   rowptr = (int*)  alloc((size_t)(n+1)*4);
  int*   col    = (int*)  alloc((size_t)E*4);
  float* dis    = (float*)alloc((size_t)n*4);
  __hip_bfloat16* bufB = (__hip_bfloat16*)alloc((size_t)n*64*2);  // H' (gathered) in bf16
  float* bufC   = (float*)alloc((size_t)n*64*4);                   // agg output fp32
  float* stats  = (float*)alloc(4*128*4);
  int*   gs     = (int*)  alloc((size_t)(G+1)*4);
  float* pooled = (float*)alloc((size_t)G*64*4);
  unsigned* ebuf = (unsigned*)bufB;   // alias: dead before gemm1 writes bufB (12.8MB > 6.4MB needed)

  hipMemsetAsync(bhist, 0, (size_t)nb*4, stream);
  hipMemsetAsync(stats, 0, 4*128*4, stream);

  size_t ldsb = (size_t)nb*4;
  k_bhist<<<256,256,ldsb,stream>>>(dst, E, nb, bhist);
  k_bscan<<<1,256,0,stream>>>(bhist, nb, boff, bcur, rowptr, n, E);
  int nchunk = (E + 255) / 256;
  k_bscatter<<<256,256,ldsb,stream>>>(src, dst, E, nb, nchunk, bcur, ebuf);
  k_bsort<<<nb,256,0,stream>>>(ebuf, boff, n, rowptr, col, dis);
  k_gsinit<<<4,256,0,stream>>>(gs, G, n);
  k_gsbound<<<512,256,0,stream>>>(batch, n, gs);

  int ntiles = (n + 15) / 16;
  int gg  = (ntiles + 3) / 4;

  // layer 1
  k_gemm<128,false><<<gg,256,0,stream>>>(x, W1, dis, nullptr, nullptr, nullptr, bufB, n, ntiles);
  k_agg<<<2048,256,0,stream>>>(bufB, rowptr, col, dis, b1, bufC, stats+0, n);
  // layer 2
  k_gemm<64,true><<<gg,256,0,stream>>>(bufC, W2, dis, stats+0, g2, bt2, bufB, n, ntiles);
  k_agg<<<2048,256,0,stream>>>(bufB, rowptr, col, dis, b2, bufC, stats+128, n);
  // layer 3
  k_gemm<64,true><<<gg,256,0,stream>>>(bufC, W3, dis, stats+128, g3, bt3, bufB, n, ntiles);
  k_agg<<<2048,256,0,stream>>>(bufB, rowptr, col, dis, b3, bufC, stats+256, n);
  // layer 4
  k_gemm<64,true><<<gg,256,0,stream>>>(bufC, W4, dis, stats+256, g4, bt4, bufB, n, ntiles);
  k_agg<<<2048,256,0,stream>>>(bufB, rowptr, col, dis, b4, bufC, stats+384, n);

  k_pool<<<G,256,0,stream>>>(bufC, stats+384, g4, bt4, gs, pooled, n);
  k_logits<<<(G*64 + 255)/256,256,0,stream>>>(pooled, fcW, fcb, (float*)d_out, G);
}